// Round 1
// baseline (1185.649 us; speedup 1.0000x reference)
//
#include <hip/hip_runtime.h>
#include <hip/hip_bf16.h>
#include <stdint.h>

#define BTOT  65536
#define KTR   11
#define NSLOT 12   // 11 transforms + z

typedef __attribute__((ext_vector_type(8))) short bf16x8_t;
typedef __attribute__((ext_vector_type(4))) float f32x4_t;

// Swizzled LDS activation layout: row m (128 rows x 256 bf16 cols), 16B groups
// rotated by row index so A-frag ds_read_b128 (16 rows, same k-offset) spreads
// across banks (2-way max, free per m136). Returns ELEMENT offset.
__device__ __forceinline__ int act_addr(int m, int n) {
    return m * 256 + ((((n >> 3) + m) & 31) << 3) + (n & 7);
}

__device__ __forceinline__ float gelu_exact(float x) {
    return 0.5f * x * (1.0f + erff(x * 0.70710678118654752440f));
}

__global__ void cast_x_kernel(const float* __restrict__ x, __hip_bfloat16* __restrict__ xb) {
    int i = (blockIdx.x * 256 + threadIdx.x) * 4;
    float4 v = *(const float4*)(x + i);
    union { __hip_bfloat16 h[4]; uint64_t u; } o;
    o.h[0] = __float2bfloat16(v.x);
    o.h[1] = __float2bfloat16(v.y);
    o.h[2] = __float2bfloat16(v.z);
    o.h[3] = __float2bfloat16(v.w);
    *(uint64_t*)(xb + i) = o.u;
}

// out[b][c][r] = in[b][r][c], cast fp32 -> bf16. R, C multiples of 32.
__global__ void transpose_cast_kernel(const float* __restrict__ in,
                                      __hip_bfloat16* __restrict__ out,
                                      int R, int C) {
    __shared__ float tile[32][33];
    int tpc = C >> 5;
    int tr = (blockIdx.x / tpc) << 5;
    int tc = (blockIdx.x % tpc) << 5;
    const float* bi = in + (size_t)blockIdx.y * R * C;
    __hip_bfloat16* bo = out + (size_t)blockIdx.y * R * C;
    int lx = threadIdx.x & 31, ly = threadIdx.x >> 5;
    #pragma unroll
    for (int r = 0; r < 32; r += 8)
        tile[ly + r][lx] = bi[(size_t)(tr + ly + r) * C + tc + lx];
    __syncthreads();
    #pragma unroll
    for (int r = 0; r < 32; r += 8)
        bo[(size_t)(tc + ly + r) * R + tr + lx] = __float2bfloat16(tile[lx][ly + r]);
}

// One GEMM stage: act[128][256] (LDS, bf16, swizzled)  <-  f(act @ W + bias)
// Wt is W transposed: Wt[n][k], row-major [256][256] bf16 in global (L2-hot).
// Per wave: 8 m-tiles x 4 n-tiles of 16x16x32 bf16 MFMA, K-loop 8 chunks of 32.
__device__ void run_stage(__hip_bfloat16* act,
                          const __hip_bfloat16* __restrict__ Wt,
                          const float* __restrict__ bias,
                          bool do_gelu, int wave, int lane)
{
    const int lr = lane & 15;   // A-row / B-col / C-col within tile
    const int q  = lane >> 4;   // quad -> k-octet (operands), row group (C)
    const int n0 = wave * 64;

    f32x4_t acc[8][4];
    #pragma unroll
    for (int mi = 0; mi < 8; ++mi)
        #pragma unroll
        for (int ni = 0; ni < 4; ++ni)
            acc[mi][ni] = (f32x4_t){0.f, 0.f, 0.f, 0.f};

    // prefetch B-frags for kc=0
    bf16x8_t bcur[4];
    #pragma unroll
    for (int ni = 0; ni < 4; ++ni)
        bcur[ni] = *(const bf16x8_t*)(Wt + (size_t)(n0 + (ni << 4) + lr) * 256 + q * 8);

    #pragma unroll 1
    for (int kc = 0; kc < 8; ++kc) {
        const int kof = kc * 32 + q * 8;
        bf16x8_t bnxt[4];
        if (kc < 7) {
            #pragma unroll
            for (int ni = 0; ni < 4; ++ni)
                bnxt[ni] = *(const bf16x8_t*)(Wt + (size_t)(n0 + (ni << 4) + lr) * 256 + kof + 32);
        }
        bf16x8_t af[8];
        #pragma unroll
        for (int mi = 0; mi < 8; ++mi)
            af[mi] = *(const bf16x8_t*)(act + act_addr((mi << 4) + lr, kof));
        #pragma unroll
        for (int mi = 0; mi < 8; ++mi)
            #pragma unroll
            for (int ni = 0; ni < 4; ++ni)
                acc[mi][ni] = __builtin_amdgcn_mfma_f32_16x16x32_bf16(af[mi], bcur[ni], acc[mi][ni], 0, 0, 0);
        #pragma unroll
        for (int ni = 0; ni < 4; ++ni) bcur[ni] = bnxt[ni];
    }

    float bv[4];
    #pragma unroll
    for (int ni = 0; ni < 4; ++ni) bv[ni] = bias[n0 + (ni << 4) + lr];

    __syncthreads();   // all waves done reading act before overwrite
    #pragma unroll
    for (int mi = 0; mi < 8; ++mi) {
        #pragma unroll
        for (int ni = 0; ni < 4; ++ni) {
            const int n = n0 + (ni << 4) + lr;
            #pragma unroll
            for (int r = 0; r < 4; ++r) {
                float v = acc[mi][ni][r] + bv[ni];
                if (do_gelu) v = gelu_exact(v);
                // C-layout: col = lane&15, row = (lane>>4)*4 + r   [m89/m91]
                act[act_addr((mi << 4) + (q << 2) + r, n)] = __float2bfloat16(v);
            }
        }
    }
    __syncthreads();
}

__launch_bounds__(256, 2)
__global__ void chain_kernel(const __hip_bfloat16* __restrict__ xb,
                             const __hip_bfloat16* __restrict__ Tw1t,
                             const float* __restrict__ Tb1,
                             const __hip_bfloat16* __restrict__ Tw2t,
                             const float* __restrict__ Tb2,
                             const __hip_bfloat16* __restrict__ Ew1t,
                             const float* __restrict__ Eb1,
                             const __hip_bfloat16* __restrict__ Ew2t,
                             const float* __restrict__ Eb2,
                             __hip_bfloat16* __restrict__ zbuf,
                             int b0, int chunk_rows)
{
    __shared__ __align__(16) __hip_bfloat16 act[128 * 256];   // 64 KB exactly
    const int tid  = threadIdx.x;
    const int wave = tid >> 6, lane = tid & 63;
    const int slot = blockIdx.y;   // 0..10 = transforms, 11 = z path
    const int tile = blockIdx.x;

    // stage x tile into LDS (coalesced 16B global reads -> swizzled ds_write_b128)
    #pragma unroll
    for (int i = 0; i < 16; ++i) {
        int lin = i * 256 + tid;
        int r = lin >> 5, g = lin & 31;
        bf16x8_t v = *(const bf16x8_t*)(xb + (size_t)(b0 + tile * 128 + r) * 256 + g * 8);
        *(bf16x8_t*)(act + act_addr(r, g * 8)) = v;
    }
    __syncthreads();

    if (slot < KTR) {   // uniform per block (blockIdx.y)
        run_stage(act, Tw1t + (size_t)slot * 65536, Tb1 + slot * 256, true,  wave, lane);
        run_stage(act, Tw2t + (size_t)slot * 65536, Tb2 + slot * 256, false, wave, lane);
    }
    run_stage(act, Ew1t, Eb1, true,  wave, lane);
    run_stage(act, Ew2t, Eb2, false, wave, lane);

    // act now holds zt (or z) tile in bf16; coalesced copy-out
    __hip_bfloat16* dst = zbuf + ((size_t)slot * chunk_rows + tile * 128) * 256;
    #pragma unroll
    for (int i = 0; i < 16; ++i) {
        int lin = i * 256 + tid;
        int r = lin >> 5, g = lin & 31;
        bf16x8_t v = *(const bf16x8_t*)(act + act_addr(r, g * 8));
        *(bf16x8_t*)(dst + (size_t)r * 256 + g * 8) = v;
    }
}

// Per row b: G = Z Z^T (12x12 over H=256) via mfma(v, v, acc) — A-frag == B-frag.
// One wave per row.
__launch_bounds__(256, 4)
__global__ void reduce_kernel(const __hip_bfloat16* __restrict__ zbuf,
                              float* __restrict__ out, int b0, int chunk_rows)
{
    __shared__ float Gs[4][16][17];
    __shared__ float Ss[4][12][12];
    __shared__ float Ns[4][16];
    const int tid  = threadIdx.x;
    const int wave = tid >> 6, lane = tid & 63;
    const int lb   = blockIdx.x * 4 + wave;   // local row in chunk
    const int lr = lane & 15, q = lane >> 4;
    const int slot = lr < NSLOT ? lr : NSLOT - 1;  // clamp; G rows/cols >=12 unused

    f32x4_t acc = (f32x4_t){0.f, 0.f, 0.f, 0.f};
    #pragma unroll
    for (int kc = 0; kc < 8; ++kc) {
        bf16x8_t v = *(const bf16x8_t*)(zbuf + ((size_t)slot * chunk_rows + lb) * 256 + kc * 32 + q * 8);
        acc = __builtin_amdgcn_mfma_f32_16x16x32_bf16(v, v, acc, 0, 0, 0);
    }
    #pragma unroll
    for (int r = 0; r < 4; ++r)
        Gs[wave][(q << 2) + r][lr] = acc[r];
    __syncthreads();
    if (lane < 12) Ns[wave][lane] = sqrtf(Gs[wave][lane][lane]);
    __syncthreads();
    if (lane < 55) {             // 55 transform pairs l<k<11
        int c = lane, k = 1;
        while (c >= k) { c -= k; ++k; }
        int l = c;
        float e = expf(Gs[wave][l][k] / fmaxf(Ns[wave][l] * Ns[wave][k], 1e-8f));
        Ss[wave][l][k] = e;
        Ss[wave][k][l] = e;
    }
    __syncthreads();
    float term = 0.f;
    if (lane < 11) {
        int k = lane;
        float neg = 0.f;
        #pragma unroll
        for (int l = 0; l < 11; ++l)
            if (l != k) neg += Ss[wave][l][k];
        float cz = Gs[wave][11][k] / fmaxf(Ns[wave][11] * Ns[wave][k], 1e-8f);
        term = logf(expf(cz) + neg) - cz;   // -log(sim/(sim+neg))
    }
    term += __shfl_xor(term, 1);
    term += __shfl_xor(term, 2);
    term += __shfl_xor(term, 4);
    term += __shfl_xor(term, 8);
    if (lane == 0) out[b0 + lb] = term;
}

extern "C" void kernel_launch(void* const* d_in, const int* in_sizes, int n_in,
                              void* d_out, int out_size, void* d_ws, size_t ws_size,
                              hipStream_t stream)
{
    const float* x   = (const float*)d_in[0];
    const float* Tw1 = (const float*)d_in[1];
    const float* Tb1 = (const float*)d_in[2];
    const float* Tw2 = (const float*)d_in[3];
    const float* Tb2 = (const float*)d_in[4];
    const float* Ew1 = (const float*)d_in[5];
    const float* Eb1 = (const float*)d_in[6];
    const float* Ew2 = (const float*)d_in[7];
    const float* Eb2 = (const float*)d_in[8];
    float* out = (float*)d_out;

    char* ws = (char*)d_ws;
    const size_t off_xb  = 0;
    const size_t off_tw1 = off_xb  + (size_t)BTOT * 256 * 2;   // 32 MB
    const size_t off_tw2 = off_tw1 + (size_t)KTR * 65536 * 2;
    const size_t off_ew1 = off_tw2 + (size_t)KTR * 65536 * 2;
    const size_t off_ew2 = off_ew1 + (size_t)65536 * 2;
    const size_t off_z   = off_ew2 + (size_t)65536 * 2;

    __hip_bfloat16* xb   = (__hip_bfloat16*)(ws + off_xb);
    __hip_bfloat16* Tw1t = (__hip_bfloat16*)(ws + off_tw1);
    __hip_bfloat16* Tw2t = (__hip_bfloat16*)(ws + off_tw2);
    __hip_bfloat16* Ew1t = (__hip_bfloat16*)(ws + off_ew1);
    __hip_bfloat16* Ew2t = (__hip_bfloat16*)(ws + off_ew2);
    __hip_bfloat16* zbuf = (__hip_bfloat16*)(ws + off_z);

    // Chunk batch dim if scratch is too small for the full 384 MB zt buffer.
    long long zbytes = (long long)ws_size - (long long)off_z;
    long long rows_cap = zbytes > 0 ? zbytes / ((long long)NSLOT * 256 * 2) : 0;
    int chunk = (int)((rows_cap / 128) * 128);
    if (chunk > BTOT) chunk = BTOT;
    if (chunk < 128) chunk = 128;

    cast_x_kernel<<<dim3(BTOT * 256 / 1024), 256, 0, stream>>>(x, xb);
    transpose_cast_kernel<<<dim3(64, KTR), 256, 0, stream>>>(Tw1, Tw1t, 256, 256);
    transpose_cast_kernel<<<dim3(64, KTR), 256, 0, stream>>>(Tw2, Tw2t, 256, 256);
    transpose_cast_kernel<<<dim3(64, 1),   256, 0, stream>>>(Ew1, Ew1t, 256, 256);
    transpose_cast_kernel<<<dim3(64, 1),   256, 0, stream>>>(Ew2, Ew2t, 256, 256);

    for (int b0 = 0; b0 < BTOT; b0 += chunk) {
        int rows = (BTOT - b0 < chunk) ? (BTOT - b0) : chunk;
        chain_kernel<<<dim3(rows / 128, NSLOT), 256, 0, stream>>>(
            xb, Tw1t, Tb1, Tw2t, Tb2, Ew1t, Eb1, Ew2t, Eb2, zbuf, b0, rows);
        reduce_kernel<<<dim3(rows / 4), 256, 0, stream>>>(zbuf, out, b0, rows);
    }
}